// Round 7
// baseline (76.378 us; speedup 1.0000x reference)
//
#include <hip/hip_runtime.h>
#include <math.h>

#define B 2
#define T 2048
#define D 512
#define KW 64
#define SCALE 0.044194173824159216f   // 1/sqrt(512)

typedef __attribute__((ext_vector_type(8))) short short8;   // 8 bf16 (4 VGPRs)
typedef __attribute__((ext_vector_type(4))) float f32x4;    // MFMA C/D
typedef __attribute__((ext_vector_type(4))) int   i32x4;

// float -> bf16 (RNE)
__device__ __forceinline__ ushort f2bf(float f) {
  union { float f; unsigned u; } v; v.f = f;
  unsigned r = v.u + 0x7fffu + ((v.u >> 16) & 1u);
  return (ushort)(r >> 16);
}

// tanh-form gelu (|err| < ~1e-3, under bf16 rounding noise)
__device__ __forceinline__ float gelu_fast(float v) {
  float v2 = v * v;
  float u  = fmaf(v2 * v, 0.03567740814f, 0.7978845608f * v);
  float e  = __builtin_amdgcn_exp2f(2.885390082f * u);
  float r  = __builtin_amdgcn_rcpf(1.f + e);
  return fmaf(-v, r, v);
}

// ---------------------------------------------------------------------------
// Fully fused kernel: one block per 16-t tile (4 waves), one dispatch total.
//
// Window ownership (zero duplication): lane (wv, quad, n) holds conv rows
// w = 16*jc + n (w = t - (t0-63), jc in [0,5)), cols wv*128 + i*32 + quad*8
// + [0,8) (i in [0,4)) => bfr[i][jc] IS the energy MFMA B-fragment set and
// collectively IS the whole 80x512 window. Conv is computed straight into
// these registers; q/qT never touch global memory.
//
// Energy A-frags: row t0+n = window row 63+n = lane (quad, n-1)'s jc=4 row
// (n=0 -> lane (quad,15)'s jc=3 row) => one __shfl + select per dword.
//
// Context: ctx[t][c] = sum_j' A'[t][j'] * qwin[w=j'-1][c]  (A' = attn,
// col j' = key j+1; cols 0 and 81..95 zero). B-frags need column-walks, so
// each ks-chunk (32 k) round-trips a per-wave 32-row band slab through LDS:
//   element (w', c_local) at  w'*128 + ((c_local + 16*(w'>>3)) & 127)
// The 16*quad rotation makes the u16 gather conflict-free
// (bank = 8*((ncl+quad)&3) + (n>>1): 32 distinct, 2 lanes/bank same-word).
//
// LDS: bands 32K + s_E 15K + s_attn 3K + s_x 0.3K = 51.5 KB (< 64 KB).
// ---------------------------------------------------------------------------
__global__ __launch_bounds__(256, 1) void k_fused(
    const float* __restrict__ x, const float* __restrict__ w,
    const float* __restrict__ bias, const float* __restrict__ gate,
    float* __restrict__ out) {
  __shared__ float s_x[84];
  __shared__ alignas(16) ushort s_band[4][32 * 128];   // 32768 B, per-wave slabs
  __shared__ alignas(16) f32x4 s_E[3][5][64];          // 15360 B
  __shared__ alignas(16) ushort s_attn[16 * 96];       // 3072 B

  int blk  = blockIdx.x;                    // 256 blocks = 1/CU
  int tile = (blk & 7) * 32 + (blk >> 3);   // XCD k -> contiguous 512-t range
  int b  = tile >> 7;
  int t0 = (tile & 127) << 4;
  int tid  = threadIdx.x;
  int wv   = tid >> 6;
  int lane = tid & 63;
  int n    = lane & 15;
  int quad = lane >> 4;

  // ---- stage x window: s_x[idx] = x[t0-64+idx], idx in [0,82) ------------
  if (tid < 82) {
    int tx = t0 - 64 + tid;
    s_x[tid] = (tx >= 0 && tx < T) ? x[b * T + tx] : 0.f;
  }
  __syncthreads();

  // ---- conv+gelu directly into B-fragment registers ----------------------
  // xv[jc] = x at row t = t0-63+16jc+n  ->  s_x index 16jc+n+1
  float xv[5][3];
  bool vrow[5];
#pragma unroll
  for (int jc = 0; jc < 5; ++jc) {
    int idx = 16 * jc + n + 1;
    xv[jc][0] = s_x[idx - 1];
    xv[jc][1] = s_x[idx];
    xv[jc][2] = s_x[idx + 1];
    int rowt = t0 - 63 + 16 * jc + n;
    vrow[jc] = (rowt >= 0) && (rowt < T);
  }

  short8 bfr[4][5];
#pragma unroll
  for (int i = 0; i < 4; ++i) {
    int c0g = wv * 128 + i * 32 + quad * 8;     // 8 cols, c0g % 8 == 0
    float wreg[24], breg[8];
#pragma unroll
    for (int v4 = 0; v4 < 6; ++v4)
      *(float4*)&wreg[v4 * 4] = *(const float4*)(w + (size_t)c0g * 3 + v4 * 4);
    *(float4*)&breg[0] = *(const float4*)(bias + c0g);
    *(float4*)&breg[4] = *(const float4*)(bias + c0g + 4);
#pragma unroll
    for (int jc = 0; jc < 5; ++jc) {
      short8 h;
#pragma unroll
      for (int e = 0; e < 8; ++e) {
        float val = fmaf(xv[jc][0], wreg[e * 3],
                    fmaf(xv[jc][1], wreg[e * 3 + 1],
                    fmaf(xv[jc][2], wreg[e * 3 + 2], breg[e])));
        float g = vrow[jc] ? gelu_fast(val) : 0.f;
        h[e] = (short)f2bf(g);
      }
      bfr[i][jc] = h;
    }
  }

  // ---- energy A-frags: shfl from bfr[.][4] (n>0) / bfr[.][3] (n==0) ------
  int src = (lane & 48) | ((n + 15) & 15);    // quad*16 + (n-1)&15
  short8 afr[4];
#pragma unroll
  for (int i = 0; i < 4; ++i) {
    i32x4 v4 = *(i32x4*)&bfr[i][4];
    i32x4 v3 = *(i32x4*)&bfr[i][3];
    i32x4 p;
#pragma unroll
    for (int k = 0; k < 4; ++k) {
      int a4 = __shfl(v4[k], src, 64);
      int a3 = __shfl(v3[k], src, 64);
      p[k] = (n == 0) ? a3 : a4;
    }
    afr[i] = *(short8*)&p;
  }

  // ---- energy MFMA: E[m=t][j] partial over this wave's 128 channels ------
  f32x4 acc[5];
#pragma unroll
  for (int jc = 0; jc < 5; ++jc) acc[jc] = (f32x4){0.f, 0.f, 0.f, 0.f};
#pragma unroll
  for (int i = 0; i < 4; ++i)
#pragma unroll
    for (int jc = 0; jc < 5; ++jc)
      acc[jc] = __builtin_amdgcn_mfma_f32_16x16x32_bf16(afr[i], bfr[i][jc],
                                                        acc[jc], 0, 0, 0);

  // ---- cross-wave reduce: waves 1..3 publish, wave 0 sums + softmax ------
  if (wv) {
#pragma unroll
    for (int jc = 0; jc < 5; ++jc) s_E[wv - 1][jc][lane] = acc[jc];
  }
  __syncthreads();

  if (wv == 0) {
#pragma unroll
    for (int ww = 0; ww < 3; ++ww)
#pragma unroll
      for (int jc = 0; jc < 5; ++jc) {
        f32x4 v = s_E[ww][jc][lane];
        acc[jc][0] += v[0]; acc[jc][1] += v[1];
        acc[jc][2] += v[2]; acc[jc][3] += v[3];
      }
    // band-masked softmax over j, rows m = quad*4+r
#pragma unroll
    for (int r = 0; r < 4; ++r) {
      int m = quad * 4 + r;
      float e[5];
      float mx = -1e30f;
#pragma unroll
      for (int jc = 0; jc < 5; ++jc) {
        int j = jc * 16 + n;
        bool valid = (j >= m) && (j <= m + (KW - 1));
        e[jc] = valid ? acc[jc][r] * SCALE : -1e30f;
        mx = fmaxf(mx, e[jc]);
      }
#pragma unroll
      for (int off = 1; off <= 8; off <<= 1) mx = fmaxf(mx, __shfl_xor(mx, off, 64));
      float p[5];
      float s = 0.f;
#pragma unroll
      for (int jc = 0; jc < 5; ++jc) {
        p[jc] = (e[jc] > -1e29f) ? __expf(e[jc] - mx) : 0.f;
        s += p[jc];
      }
#pragma unroll
      for (int off = 1; off <= 8; off <<= 1) s += __shfl_xor(s, off, 64);
      float inv = 1.f / s;
      // A' row m: col j+1 = attn; cols {0, 81..95} = 0
#pragma unroll
      for (int jc = 0; jc < 5; ++jc) {
        int j = jc * 16 + n;
        s_attn[m * 96 + j + 1] = f2bf(p[jc] * inv);
      }
      int jp = (n == 0) ? 0 : (80 + n);
      s_attn[m * 96 + jp] = 0;
    }
  }

  // ---- context: band slabs through per-wave LDS --------------------------
  ushort* slab = s_band[wv];
  const short8 zero8 = {0, 0, 0, 0, 0, 0, 0, 0};

  // write band ks: rows w_full in [32ks-1, 32ks+30], w' = w_full-(32ks-1)
#define WRITE_BAND(KS)                                                        \
  {                                                                           \
    _Pragma("unroll")                                                         \
    for (int i = 0; i < 4; ++i) {           /* (b) w'=n+1, frag jc=2ks */     \
      int wp = n + 1;                                                         \
      int off = wp * 128 + ((i * 32 + quad * 8 + 16 * (wp >> 3)) & 127);      \
      *(short8*)(slab + off) = bfr[i][2 * (KS)];                              \
    }                                                                         \
    if (n == 15) {                          /* (a) w'=0 */                    \
      _Pragma("unroll")                                                       \
      for (int i = 0; i < 4; ++i) {                                           \
        int off = (i * 32 + quad * 8) & 127;                                  \
        *(short8*)(slab + off) = ((KS) == 0) ? zero8 : bfr[i][2 * (KS) - 1];  \
      }                                                                       \
    }                                                                         \
    if (n <= 14) {                          /* (c) w'=17+n */                 \
      _Pragma("unroll")                                                       \
      for (int i = 0; i < 4; ++i) {                                           \
        int wp = 17 + n;                                                      \
        int off = wp * 128 + ((i * 32 + quad * 8 + 16 * (wp >> 3)) & 127);    \
        *(short8*)(slab + off) = ((KS) == 2) ? zero8 : bfr[i][2 * (KS) + 1];  \
      }                                                                       \
    }                                                                         \
  }

  // gather B2 frag for (ks-band already in slab, chunk ncl):
  // B2[k=quad*8+jj][c=ncl*16+n] = slab[(quad*8+jj)*128 + rot(c)]
#define GATHER_B2(dst, NCL)                                                   \
  {                                                                           \
    const ushort* gp = slab + quad * 8 * 128 +                                \
                       (((NCL) * 16 + n + 16 * quad) & 127);                  \
    _Pragma("unroll")                                                         \
    for (int jj = 0; jj < 8; ++jj) (dst)[jj] = (short)gp[jj * 128];           \
  }

  // band 0: write + prefetch gathers (overlaps wave 0's softmax)
  WRITE_BAND(0)
  short8 b2pre[8];
#pragma unroll
  for (int ncl = 0; ncl < 8; ++ncl) GATHER_B2(b2pre[ncl], ncl)
  __syncthreads();

  // A'-frags (attn) for the 3 ks chunks
  short8 afr2[3];
#pragma unroll
  for (int ks = 0; ks < 3; ++ks)
    afr2[ks] = *(const short8*)(s_attn + n * 96 + ks * 32 + quad * 8);

  f32x4 co[8];
#pragma unroll
  for (int ncl = 0; ncl < 8; ++ncl) {
    co[ncl] = (f32x4){0.f, 0.f, 0.f, 0.f};
    co[ncl] = __builtin_amdgcn_mfma_f32_16x16x32_bf16(afr2[0], b2pre[ncl],
                                                      co[ncl], 0, 0, 0);
  }

  WRITE_BAND(1)
#pragma unroll
  for (int ncl = 0; ncl < 8; ++ncl) {
    short8 b2;
    GATHER_B2(b2, ncl)
    co[ncl] = __builtin_amdgcn_mfma_f32_16x16x32_bf16(afr2[1], b2,
                                                      co[ncl], 0, 0, 0);
  }

  WRITE_BAND(2)
#pragma unroll
  for (int ncl = 0; ncl < 8; ++ncl) {
    short8 b2;
    GATHER_B2(b2, ncl)
    co[ncl] = __builtin_amdgcn_mfma_f32_16x16x32_bf16(afr2[2], b2,
                                                      co[ncl], 0, 0, 0);
  }

  // ---- scale + store (coalesced float4 along t in (b,c,t) layout) --------
  const float tg = tanhf(gate[0]);
#pragma unroll
  for (int ncl = 0; ncl < 8; ++ncl) {
    int c = (wv * 8 + ncl) * 16 + n;
    f32x4 o;
    o[0] = co[ncl][0] * tg; o[1] = co[ncl][1] * tg;
    o[2] = co[ncl][2] * tg; o[3] = co[ncl][3] * tg;
    *(f32x4*)(out + ((size_t)b * D + c) * T + t0 + quad * 4) = o;
  }
}

// ---------------------------------------------------------------------------
extern "C" void kernel_launch(void* const* d_in, const int* in_sizes, int n_in,
                              void* d_out, int out_size, void* d_ws, size_t ws_size,
                              hipStream_t stream) {
  const float* x      = (const float*)d_in[0];   // (B,1,T)
  const float* conv_w = (const float*)d_in[1];   // (D,1,3)
  const float* conv_b = (const float*)d_in[2];   // (D,)
  const float* gate   = (const float*)d_in[3];   // scalar
  float* out = (float*)d_out;                    // (B,D,T)

  // single fused dispatch; d_ws unused (conv window lives in registers/LDS)
  k_fused<<<B * T / 16, 256, 0, stream>>>(x, conv_w, conv_b, gate, out);
}